// Round 7
// baseline (500.928 us; speedup 1.0000x reference)
//
#include <hip/hip_runtime.h>

// PointPillarScatter, wave-specialized LDS-transposed scatter (R6 minus nt):
//   pass 1: winner[b*SS+s] = max p writing (b,s)  (last-write-wins, verified R1)
//   pass 2: block owns 2048 slots; 8 channel-group passes through a channel-major
//           64KB LDS tile ([8][2048], bank-conflict-free both sides); each wave
//           owns 2 planes per pass and writes each as an 8KB LINEAR run.
//   R7 probe: PLAIN stores (no __builtin_nontemporal_store) — single-variable
//   test of whether the nt/L2-bypass path was capping write BW at ~2.4 TB/s.

#define NXx 432
#define NYy 496
#define SS  (NXx * NYy)   // 214272; SS % 256 == 0
#define CC  64
#define TS  2048          // slots per block; nslots % TS == 0 -> 837 blocks
#define CG  8             // channels per pass; CC/CG = 8 passes

typedef float f4 __attribute__((ext_vector_type(4)));

__global__ void winner_kernel(const int* __restrict__ cb,
                              const int* __restrict__ cz,
                              const int* __restrict__ cy,
                              const int* __restrict__ cx,
                              int* __restrict__ winner, int P) {
    int p = blockIdx.x * blockDim.x + threadIdx.x;
    if (p < P) {
        int slot = cb[p] * SS + cz[p] + cy[p] * NXx + cx[p];
        atomicMax(&winner[slot], p);
    }
}

__global__ __launch_bounds__(256)
void scatter_kernel(const float* __restrict__ pf,
                    const int* __restrict__ winner,
                    float* __restrict__ out) {
    __shared__ float lds[CG][TS];       // 64 KB, channel-major
    const int t    = threadIdx.x;
    const int wave = t >> 6;            // 0..3
    const int lane = t & 63;
    const int slot0 = blockIdx.x * TS;

    // Winners for my 8 strided slots, loaded once (coalesced).
    int w[8];
    #pragma unroll
    for (int k = 0; k < 8; ++k) w[k] = winner[slot0 + k * 256 + t];

    for (int cg = 0; cg < CC / CG; ++cg) {
        // ---- phase 1: gather CG-channel chunk of each winner row into LDS ----
        #pragma unroll
        for (int k = 0; k < 8; ++k) {
            const int sl = k * 256 + t;
            float v[CG];
            if (w[k] >= 0) {
                const f4* row = reinterpret_cast<const f4*>(
                    pf + (size_t)w[k] * CC + cg * CG);
                f4 a = row[0], bq = row[1];
                v[0]=a.x;  v[1]=a.y;  v[2]=a.z;  v[3]=a.w;
                v[4]=bq.x; v[5]=bq.y; v[6]=bq.z; v[7]=bq.w;
            } else {
                #pragma unroll
                for (int c = 0; c < CG; ++c) v[c] = 0.0f;
            }
            #pragma unroll
            for (int c = 0; c < CG; ++c)
                lds[c][sl] = v[c];      // lanes hit banks t&31 -> 2-way, free
        }
        __syncthreads();

        // ---- phase 2: each wave streams 2 planes as 8KB linear runs ----
        #pragma unroll
        for (int pl = 0; pl < 2; ++pl) {
            const int c = wave * 2 + pl;            // local channel 0..7
            const int gc = cg * CG + c;             // global channel
            #pragma unroll
            for (int i = 0; i < 8; ++i) {
                const int off = i * 256 + 4 * lane; // chunk never straddles batch
                f4 v = *reinterpret_cast<const f4*>(&lds[c][off]); // b128 stride-1
                const int gs = slot0 + off;
                const int b  = gs / SS;             // magic-mul const divide
                const int s  = gs - b * SS;
                *reinterpret_cast<f4*>(out + (size_t)(b * CC + gc) * SS + s) = v;
            }
        }
        __syncthreads();
    }
}

extern "C" void kernel_launch(void* const* d_in, const int* in_sizes, int n_in,
                              void* d_out, int out_size, void* d_ws, size_t ws_size,
                              hipStream_t stream) {
    const float* pf = (const float*)d_in[0];
    const int* cb   = (const int*)d_in[1];
    const int* cz   = (const int*)d_in[2];
    const int* cy   = (const int*)d_in[3];
    const int* cx   = (const int*)d_in[4];
    float* out      = (float*)d_out;

    const int P      = in_sizes[1];          // number of pillars
    const int nslots = out_size / CC;        // B * SS = 1,714,176 (TS-divisible)

    int* winner = (int*)d_ws;                // nslots ints = 6.86 MB
    hipMemsetAsync(winner, 0xFF, (size_t)nslots * sizeof(int), stream);  // -1

    winner_kernel<<<(P + 255) / 256, 256, 0, stream>>>(cb, cz, cy, cx, winner, P);

    scatter_kernel<<<nslots / TS, 256, 0, stream>>>(pf, winner, out);
}

// Round 8
// 484.676 us; speedup vs baseline: 1.0335x; 1.0335x over previous
//
#include <hip/hip_runtime.h>

// PointPillarScatter, wave-INDEPENDENT LDS-transposed scatter (no barriers):
//   pass 1: winner[b*SS+s] = max p writing (b,s)  (last-write-wins, verified R1)
//   pass 2: each WAVE owns 256 slots + all 64 channels, transposing through a
//           private 8KB LDS slab. No __syncthreads anywhere -> no vmcnt(0)
//           drains, no coupled phases; 5 blocks/CU = 20 independent waves/CU
//           keep the store pipe fed while other waves sit in gather latency.

#define NXx 432
#define NYy 496
#define SS  (NXx * NYy)   // 214272; SS % 256 == 0
#define CC  64
#define TSW 256           // slots per wave; 4 waves/block -> 1024 slots/block
#define CG  8             // channels per pass; CC/CG = 8 passes

typedef float f4 __attribute__((ext_vector_type(4)));

__global__ void winner_kernel(const int* __restrict__ cb,
                              const int* __restrict__ cz,
                              const int* __restrict__ cy,
                              const int* __restrict__ cx,
                              int* __restrict__ winner, int P) {
    int p = blockIdx.x * blockDim.x + threadIdx.x;
    if (p < P) {
        int slot = cb[p] * SS + cz[p] + cy[p] * NXx + cx[p];
        atomicMax(&winner[slot], p);
    }
}

__global__ __launch_bounds__(256, 5)
void scatter_kernel(const float* __restrict__ pf,
                    const int* __restrict__ winner,
                    float* __restrict__ out) {
    __shared__ float lds[4][CG][TSW];   // 32 KB total; 8 KB private per wave
    const int t    = threadIdx.x;
    const int wave = t >> 6;
    const int lane = t & 63;

    const int sbase = blockIdx.x * (4 * TSW) + wave * TSW;  // wave's slot base
    const int b  = sbase / SS;          // uniform per wave (SS % 256 == 0)
    const int s0 = sbase - b * SS;
    float* const obase = out + (size_t)(b * CC) * SS + s0 + 4 * lane;

    // Winners for my 4 slots, loaded once (coalesced).
    int w[4];
    #pragma unroll
    for (int k = 0; k < 4; ++k) w[k] = winner[sbase + k * 64 + lane];

    float (*L)[TSW] = lds[wave];        // this wave's private slab

    for (int cg = 0; cg < CC / CG; ++cg) {
        // ---- gather: CG-channel chunk of each winner row into the slab ----
        #pragma unroll
        for (int k = 0; k < 4; ++k) {
            const int sl = k * 64 + lane;
            float v[CG];
            if (w[k] >= 0) {
                const f4* row = reinterpret_cast<const f4*>(
                    pf + (size_t)w[k] * CC + cg * CG);
                f4 a = row[0], bq = row[1];
                v[0]=a.x;  v[1]=a.y;  v[2]=a.z;  v[3]=a.w;
                v[4]=bq.x; v[5]=bq.y; v[6]=bq.z; v[7]=bq.w;
            } else {
                #pragma unroll
                for (int c = 0; c < CG; ++c) v[c] = 0.0f;
            }
            #pragma unroll
            for (int c = 0; c < CG; ++c)
                L[c][sl] = v[c];        // banks t&31 -> 2-way, free
        }
        __builtin_amdgcn_wave_barrier();   // codegen ordering only, no HW wait

        // ---- store: 8 channel runs of 1KB (64 lanes x 16B contiguous) ----
        #pragma unroll
        for (int c = 0; c < CG; ++c) {
            f4 v = *reinterpret_cast<const f4*>(&L[c][4 * lane]);
            *reinterpret_cast<f4*>(obase + (size_t)(cg * CG + c) * SS) = v;
        }
        __builtin_amdgcn_wave_barrier();   // keep next gather from hoisting
    }
}

extern "C" void kernel_launch(void* const* d_in, const int* in_sizes, int n_in,
                              void* d_out, int out_size, void* d_ws, size_t ws_size,
                              hipStream_t stream) {
    const float* pf = (const float*)d_in[0];
    const int* cb   = (const int*)d_in[1];
    const int* cz   = (const int*)d_in[2];
    const int* cy   = (const int*)d_in[3];
    const int* cx   = (const int*)d_in[4];
    float* out      = (float*)d_out;

    const int P      = in_sizes[1];          // number of pillars
    const int nslots = out_size / CC;        // B * SS = 1,714,176

    int* winner = (int*)d_ws;                // nslots ints = 6.86 MB
    hipMemsetAsync(winner, 0xFF, (size_t)nslots * sizeof(int), stream);  // -1

    winner_kernel<<<(P + 255) / 256, 256, 0, stream>>>(cb, cz, cy, cx, winner, P);

    scatter_kernel<<<nslots / (4 * TSW), 256, 0, stream>>>(pf, winner, out);
}